// Round 1
// baseline (1649.779 us; speedup 1.0000x reference)
//
#include <hip/hip_runtime.h>
#include <stdint.h>

typedef float f32x4 __attribute__((ext_vector_type(4)));
typedef short s16x8 __attribute__((ext_vector_type(8)));

#define B_SZ 256
#define A_RG 196
#define DVD  2048
#define RNN  1024
#define H_SZ 512

__device__ __forceinline__ unsigned short f2bf(float f) {
    unsigned u = __builtin_bit_cast(unsigned, f);
    u = u + 0x7FFFu + ((u >> 16) & 1u);   // RNE
    return (unsigned short)(u >> 16);
}

// ---------------------------------------------------------------------------
// Kernel 1: W_v [2048,512] fp32 -> Wt [512,2048] bf16 (transposed for k-contig
// B-fragment loads). 256 blocks x 256 threads, 64x64 tiles via LDS.
// ---------------------------------------------------------------------------
__global__ __launch_bounds__(256) void k_prepW(const float* __restrict__ Wv,
                                               unsigned short* __restrict__ Wt) {
    __shared__ float tile[64][65];
    int kt = blockIdx.x >> 3, ct = blockIdx.x & 7;   // 32 k-tiles x 8 c-tiles
    int k0 = kt * 64, c0 = ct * 64;
    int t = threadIdx.x;
    int cl = t & 63, rq = t >> 6;
#pragma unroll
    for (int i = 0; i < 16; ++i) {
        int r = rq * 16 + i;
        tile[r][cl] = Wv[(size_t)(k0 + r) * H_SZ + c0 + cl];
    }
    __syncthreads();
    int kl = t & 63;
#pragma unroll
    for (int i = 0; i < 16; ++i) {
        int cr = rq * 16 + i;
        Wt[(size_t)(c0 + cr) * DVD + k0 + kl] = f2bf(tile[kl][cr]);
    }
}

// ---------------------------------------------------------------------------
// Kernel 2: base[b,h] = h_att[b]@W_ha + prev_h2[b]@W_hv + b_ha + b_hv + b_v
// fp32 exact. grid 256 = 64 b-groups(4 b) x 4 h-chunks(128 h), block 256.
// ---------------------------------------------------------------------------
__global__ __launch_bounds__(256) void k_base(const float* __restrict__ h_att,
                                              const float* __restrict__ prev_h2,
                                              const float* __restrict__ W_ha,
                                              const float* __restrict__ b_ha,
                                              const float* __restrict__ W_hv,
                                              const float* __restrict__ b_hv,
                                              const float* __restrict__ b_v,
                                              float* __restrict__ base_g) {
    __shared__ float ha_s[4][RNN];
    __shared__ float pv_s[4][RNN];
    int bg = blockIdx.x >> 2, hg = blockIdx.x & 3;
    int t = threadIdx.x;
#pragma unroll
    for (int i = 0; i < 16; ++i) {
        int idx = i * 256 + t;
        int bl = idx >> 10, k = idx & 1023;
        ha_s[bl][k] = h_att[(size_t)(bg * 4 + bl) * RNN + k];
        pv_s[bl][k] = prev_h2[(size_t)(bg * 4 + bl) * RNN + k];
    }
    __syncthreads();
    int h = hg * 128 + (t & 127);
    int br = t >> 7;   // 0..1 -> handles b pair {2br, 2br+1}
    float aA0 = 0, aA1 = 0, aV0 = 0, aV1 = 0;
#pragma unroll 4
    for (int k = 0; k < RNN; ++k) {
        float w1 = W_ha[(size_t)k * H_SZ + h];
        float w2 = W_hv[(size_t)k * H_SZ + h];
        aA0 = fmaf(ha_s[br * 2][k],     w1, aA0);
        aA1 = fmaf(ha_s[br * 2 + 1][k], w1, aA1);
        aV0 = fmaf(pv_s[br * 2][k],     w2, aV0);
        aV1 = fmaf(pv_s[br * 2 + 1][k], w2, aV1);
    }
    float bias = b_ha[h] + b_hv[h] + b_v[h];
    base_g[(size_t)(bg * 4 + br * 2) * H_SZ + h]     = aA0 + aV0 + bias;
    base_g[(size_t)(bg * 4 + br * 2 + 1) * H_SZ + h] = aA1 + aV1 + bias;
}

// ---------------------------------------------------------------------------
// Kernel 3 (main): per-b fused GEMM(bf16 MFMA) -> relu.Wf score -> softmax ->
// weighted sum. grid 256 (1 wg/CU), block 1024 (16 waves, wave grid 4M x 4N).
// M padded 196->256, N=512 in acc (f32x4 acc[4][8] = 128 VGPR), K-step 32.
// LDS tiles XOR-swizzled: byte ^= (row&7)<<4 (bijective; 16-way -> 2-way).
// ---------------------------------------------------------------------------
__global__ __launch_bounds__(1024, 1) void k_main(const float* __restrict__ imgs,
                                                  const unsigned short* __restrict__ Wt,
                                                  const float* __restrict__ base_g,
                                                  const float* __restrict__ W_f,
                                                  float* __restrict__ out) {
    __shared__ short At[256 * 32];      // 16 KB, swizzled [row][k]
    __shared__ short Bt[512 * 32];      // 32 KB, swizzled [col][k]
    __shared__ float bases[H_SZ];
    __shared__ float wfs[H_SZ];
    __shared__ float att_part[4][256];
    __shared__ float alpha_s[256];

    int b = blockIdx.x;
    int t = threadIdx.x;
    int lane = t & 63, w = t >> 6;

    if (t < H_SZ) bases[t] = base_g[(size_t)b * H_SZ + t];
    else          wfs[t - H_SZ] = W_f[t - H_SZ];

    const float* imgb = imgs + (size_t)b * A_RG * DVD;

    // staging assignments
    int ar  = t >> 2;            // A row 0..255
    int akq = (t & 3) * 8;       // A k-offset (8 floats -> one 16B LDS write)
    int bc  = t >> 1;            // B col 0..511
    int bkh = (t & 1) * 16;      // B k-offset (16 bf16 -> two 16B LDS writes)

    float4 rA0, rA1;
    s16x8 rB0, rB1;
    char* Atc = (char*)At;
    char* Btc = (char*)Bt;

    auto loadA = [&](int k0) {
        if (ar < A_RG) {
            const float4* p = (const float4*)(imgb + (size_t)ar * DVD + k0 + akq);
            rA0 = p[0]; rA1 = p[1];
        } else {
            rA0 = make_float4(0.f, 0.f, 0.f, 0.f);
            rA1 = make_float4(0.f, 0.f, 0.f, 0.f);
        }
    };
    auto loadB = [&](int k0) {
        const s16x8* p = (const s16x8*)(Wt + (size_t)bc * DVD + k0 + bkh);
        rB0 = p[0]; rB1 = p[1];
    };
    auto writeA = [&]() {
        s16x8 v;
        v[0] = (short)f2bf(rA0.x); v[1] = (short)f2bf(rA0.y);
        v[2] = (short)f2bf(rA0.z); v[3] = (short)f2bf(rA0.w);
        v[4] = (short)f2bf(rA1.x); v[5] = (short)f2bf(rA1.y);
        v[6] = (short)f2bf(rA1.z); v[7] = (short)f2bf(rA1.w);
        unsigned ad = (unsigned)(ar * 64 + akq * 2);
        *(s16x8*)(Atc + (ad ^ ((unsigned)(ar & 7) << 4))) = v;
    };
    auto writeB = [&]() {
        unsigned ad = (unsigned)(bc * 64 + bkh * 2);
        unsigned sw = (unsigned)(bc & 7) << 4;
        *(s16x8*)(Btc + (ad ^ sw)) = rB0;
        *(s16x8*)(Btc + ((ad + 16) ^ sw)) = rB1;
    };

    int mrow0 = (w >> 2) * 64;
    int ncol0 = (w & 3) * 128;
    int lr = lane & 15, lk = (lane >> 4) * 8;

    unsigned aAddr[4], bAddr[8];
#pragma unroll
    for (int m = 0; m < 4; ++m) {
        int r = mrow0 + m * 16 + lr;
        aAddr[m] = (unsigned)(r * 64 + lk * 2) ^ ((unsigned)(r & 7) << 4);
    }
#pragma unroll
    for (int n = 0; n < 8; ++n) {
        int c = ncol0 + n * 16 + lr;
        bAddr[n] = (unsigned)(c * 64 + lk * 2) ^ ((unsigned)(c & 7) << 4);
    }

    f32x4 acc[4][8] = {};

    loadA(0); loadB(0);
    for (int ks = 0; ks < 64; ++ks) {
        __syncthreads();              // previous MFMA reads done
        writeA(); writeB();           // (waits vmcnt for staged regs)
        __syncthreads();              // tile visible
        if (ks < 63) { loadA((ks + 1) * 32); loadB((ks + 1) * 32); }  // prefetch hides under MFMA

        s16x8 af[4], bfr[8];
#pragma unroll
        for (int m = 0; m < 4; ++m) af[m] = *(const s16x8*)(Atc + aAddr[m]);
#pragma unroll
        for (int n = 0; n < 8; ++n) bfr[n] = *(const s16x8*)(Btc + bAddr[n]);
#pragma unroll
        for (int m = 0; m < 4; ++m)
#pragma unroll
            for (int n = 0; n < 8; ++n)
                acc[m][n] = __builtin_amdgcn_mfma_f32_16x16x32_bf16(af[m], bfr[n], acc[m][n], 0, 0, 0);
    }

    // ---- epilogue: att[row] = sum_h relu(p + base[h]) * W_f[h] ----
#pragma unroll
    for (int m = 0; m < 4; ++m) {
        float p0 = 0, p1 = 0, p2 = 0, p3 = 0;
#pragma unroll
        for (int n = 0; n < 8; ++n) {
            int col = ncol0 + n * 16 + lr;
            float bs = bases[col], wfv = wfs[col];
            f32x4 a4 = acc[m][n];
            p0 += fmaxf(a4[0] + bs, 0.f) * wfv;
            p1 += fmaxf(a4[1] + bs, 0.f) * wfv;
            p2 += fmaxf(a4[2] + bs, 0.f) * wfv;
            p3 += fmaxf(a4[3] + bs, 0.f) * wfv;
        }
        float pj[4] = {p0, p1, p2, p3};
#pragma unroll
        for (int j = 0; j < 4; ++j) {
            float s = pj[j];
            s += __shfl_xor(s, 1);
            s += __shfl_xor(s, 2);
            s += __shfl_xor(s, 4);
            s += __shfl_xor(s, 8);   // sum over the 16 lanes sharing this row
            if ((lane & 15) == 0) {
                int row = mrow0 + m * 16 + (lane >> 4) * 4 + j;
                att_part[w & 3][row] = s;   // one writer per (ngroup,row): deterministic
            }
        }
    }
    __syncthreads();

    // ---- softmax over a<196 (wave 0) ----
    if (w == 0) {
        float v[4], e[4];
        float mx = -1e30f;
#pragma unroll
        for (int i = 0; i < 4; ++i) {
            int r = i * 64 + lane;
            v[i] = (r < A_RG) ? (att_part[0][r] + att_part[1][r] + att_part[2][r] + att_part[3][r])
                              : -1e30f;
            mx = fmaxf(mx, v[i]);
        }
        for (int d = 1; d < 64; d <<= 1) mx = fmaxf(mx, __shfl_xor(mx, d));
        float sum = 0.f;
#pragma unroll
        for (int i = 0; i < 4; ++i) {
            int r = i * 64 + lane;
            e[i] = (r < A_RG) ? __expf(v[i] - mx) : 0.f;
            sum += e[i];
        }
        for (int d = 1; d < 64; d <<= 1) sum += __shfl_xor(sum, d);
        float inv = 1.0f / sum;
#pragma unroll
        for (int i = 0; i < 4; ++i) alpha_s[i * 64 + lane] = e[i] * inv;
    }
    __syncthreads();

    // ---- weighted sum: out[b,d] = sum_a alpha[a]*imgs[b,a,d] (fp32 exact) ----
    float2 o = make_float2(0.f, 0.f);
    const float2* ib2 = (const float2*)imgb;
#pragma unroll 4
    for (int a = 0; a < A_RG; ++a) {
        float al = alpha_s[a];
        float2 vv = ib2[(size_t)a * (DVD / 2) + t];
        o.x = fmaf(al, vv.x, o.x);
        o.y = fmaf(al, vv.y, o.y);
    }
    ((float2*)out)[(size_t)b * (DVD / 2) + t] = o;
}

// ---------------------------------------------------------------------------
extern "C" void kernel_launch(void* const* d_in, const int* in_sizes, int n_in,
                              void* d_out, int out_size, void* d_ws, size_t ws_size,
                              hipStream_t stream) {
    const float* h_att   = (const float*)d_in[0];
    const float* prev_h2 = (const float*)d_in[1];
    const float* imgs    = (const float*)d_in[2];
    const float* W_v     = (const float*)d_in[3];
    const float* b_v     = (const float*)d_in[4];
    const float* W_ha    = (const float*)d_in[5];
    const float* b_ha    = (const float*)d_in[6];
    const float* W_hv    = (const float*)d_in[7];
    const float* b_hv    = (const float*)d_in[8];
    const float* W_f     = (const float*)d_in[9];
    // d_in[10] = b_f: softmax-invariant additive constant -> unused

    // ws layout: [0, 2MB) Wt bf16 [512][2048]; [2MB, 2.5MB) base fp32 [256][512]
    unsigned short* Wt = (unsigned short*)d_ws;
    float* base_g = (float*)((char*)d_ws + (size_t)DVD * H_SZ * 2);
    float* out = (float*)d_out;

    hipLaunchKernelGGL(k_prepW, dim3(256), dim3(256), 0, stream, W_v, Wt);
    hipLaunchKernelGGL(k_base, dim3(256), dim3(256), 0, stream,
                       h_att, prev_h2, W_ha, b_ha, W_hv, b_hv, b_v, base_g);
    hipLaunchKernelGGL(k_main, dim3(256), dim3(1024), 0, stream,
                       imgs, Wt, base_g, W_f, out);
}

// Round 2
// 425.355 us; speedup vs baseline: 3.8786x; 3.8786x over previous
//
#include <hip/hip_runtime.h>
#include <stdint.h>

typedef float f32x4 __attribute__((ext_vector_type(4)));
typedef short s16x8 __attribute__((ext_vector_type(8)));

#define B_SZ 256
#define A_RG 196
#define DVD  2048
#define RNN  1024
#define H_SZ 512

__device__ __forceinline__ unsigned short f2bf(float f) {
    unsigned u = __builtin_bit_cast(unsigned, f);
    u = u + 0x7FFFu + ((u >> 16) & 1u);   // RNE
    return (unsigned short)(u >> 16);
}

// ---------------------------------------------------------------------------
// Kernel 1: W_v [2048,512] fp32 -> Wt [512,2048] bf16 (transposed, k-contig)
// ---------------------------------------------------------------------------
__global__ __launch_bounds__(256) void k_prepW(const float* __restrict__ Wv,
                                               unsigned short* __restrict__ Wt) {
    __shared__ float tile[64][65];
    int kt = blockIdx.x >> 3, ct = blockIdx.x & 7;   // 32 k-tiles x 8 c-tiles
    int k0 = kt * 64, c0 = ct * 64;
    int t = threadIdx.x;
    int cl = t & 63, rq = t >> 6;
#pragma unroll
    for (int i = 0; i < 16; ++i) {
        int r = rq * 16 + i;
        tile[r][cl] = Wv[(size_t)(k0 + r) * H_SZ + c0 + cl];
    }
    __syncthreads();
    int kl = t & 63;
#pragma unroll
    for (int i = 0; i < 16; ++i) {
        int cr = rq * 16 + i;
        Wt[(size_t)(c0 + cr) * DVD + k0 + kl] = f2bf(tile[kl][cr]);
    }
}

// ---------------------------------------------------------------------------
// Kernel 2: base[b,h] = h_att[b]@W_ha + prev_h2[b]@W_hv + b_ha + b_hv + b_v
// ---------------------------------------------------------------------------
__global__ __launch_bounds__(256) void k_base(const float* __restrict__ h_att,
                                              const float* __restrict__ prev_h2,
                                              const float* __restrict__ W_ha,
                                              const float* __restrict__ b_ha,
                                              const float* __restrict__ W_hv,
                                              const float* __restrict__ b_hv,
                                              const float* __restrict__ b_v,
                                              float* __restrict__ base_g) {
    __shared__ float ha_s[4][RNN];
    __shared__ float pv_s[4][RNN];
    int bg = blockIdx.x >> 2, hg = blockIdx.x & 3;
    int t = threadIdx.x;
#pragma unroll
    for (int i = 0; i < 16; ++i) {
        int idx = i * 256 + t;
        int bl = idx >> 10, k = idx & 1023;
        ha_s[bl][k] = h_att[(size_t)(bg * 4 + bl) * RNN + k];
        pv_s[bl][k] = prev_h2[(size_t)(bg * 4 + bl) * RNN + k];
    }
    __syncthreads();
    int h = hg * 128 + (t & 127);
    int br = t >> 7;
    float aA0 = 0, aA1 = 0, aV0 = 0, aV1 = 0;
#pragma unroll 4
    for (int k = 0; k < RNN; ++k) {
        float w1 = W_ha[(size_t)k * H_SZ + h];
        float w2 = W_hv[(size_t)k * H_SZ + h];
        aA0 = fmaf(ha_s[br * 2][k],     w1, aA0);
        aA1 = fmaf(ha_s[br * 2 + 1][k], w1, aA1);
        aV0 = fmaf(pv_s[br * 2][k],     w2, aV0);
        aV1 = fmaf(pv_s[br * 2 + 1][k], w2, aV1);
    }
    float bias = b_ha[h] + b_hv[h] + b_v[h];
    base_g[(size_t)(bg * 4 + br * 2) * H_SZ + h]     = aA0 + aV0 + bias;
    base_g[(size_t)(bg * 4 + br * 2 + 1) * H_SZ + h] = aA1 + aV1 + bias;
}

// ---------------------------------------------------------------------------
// Kernel 3: per-(b, m-half) GEMM (bf16 MFMA, M=128 N=512 K=2048) fused with
// relu(.+base)*W_f reduce -> att_g[b, row]. Block 512 = 8 waves (2/SIMD ->
// 256-VGPR cap, acc[4][8]=128 VGPR fits without spill). Wave grid 2M x 4N,
// per-wave 64x128. LDS XOR-swizzle byte ^= (row&7)<<4 (16-way -> free 2-way).
// ---------------------------------------------------------------------------
__global__ __launch_bounds__(512, 2) void k_gemm(const float* __restrict__ imgs,
                                                 const unsigned short* __restrict__ Wt,
                                                 const float* __restrict__ base_g,
                                                 const float* __restrict__ W_f,
                                                 float* __restrict__ att_g) {
    __shared__ short At[128 * 32];      // 8 KB swizzled [row][k]
    __shared__ short Bt[512 * 32];      // 32 KB swizzled [col][k]
    __shared__ float bases[H_SZ];
    __shared__ float wfs[H_SZ];
    __shared__ float att_part[4][128];

    int bid = blockIdx.x;
    int b = bid >> 1, mh = bid & 1;
    int t = threadIdx.x;
    int lane = t & 63, w = t >> 6;

    bases[t] = base_g[(size_t)b * H_SZ + t];
    wfs[t]   = W_f[t];

    const float* imgb = imgs + (size_t)b * A_RG * DVD;
    int row0 = mh * 128;

    // staging assignments
    int ar  = t >> 2;            // A row 0..127 (4 threads/row)
    int akq = (t & 3) * 8;       // A k-offset (8 floats)
    int bc  = t;                 // B col 0..511 (1 thread/col, 32 bf16)

    float4 rA0, rA1;
    s16x8 rB[4];
    char* Atc = (char*)At;
    char* Btc = (char*)Bt;

    auto loadA = [&](int k0) {
        if (row0 + ar < A_RG) {
            const float4* p = (const float4*)(imgb + (size_t)(row0 + ar) * DVD + k0 + akq);
            rA0 = p[0]; rA1 = p[1];
        } else {
            rA0 = make_float4(0.f, 0.f, 0.f, 0.f);
            rA1 = make_float4(0.f, 0.f, 0.f, 0.f);
        }
    };
    auto loadB = [&](int k0) {
        const s16x8* p = (const s16x8*)(Wt + (size_t)bc * DVD + k0);
#pragma unroll
        for (int j = 0; j < 4; ++j) rB[j] = p[j];
    };
    auto writeA = [&]() {
        s16x8 v;
        v[0] = (short)f2bf(rA0.x); v[1] = (short)f2bf(rA0.y);
        v[2] = (short)f2bf(rA0.z); v[3] = (short)f2bf(rA0.w);
        v[4] = (short)f2bf(rA1.x); v[5] = (short)f2bf(rA1.y);
        v[6] = (short)f2bf(rA1.z); v[7] = (short)f2bf(rA1.w);
        unsigned ad = (unsigned)(ar * 64 + akq * 2);
        *(s16x8*)(Atc + (ad ^ ((unsigned)(ar & 7) << 4))) = v;
    };
    auto writeB = [&]() {
        unsigned ad = (unsigned)(bc * 64);
        unsigned sw = (unsigned)(bc & 7) << 4;
#pragma unroll
        for (int j = 0; j < 4; ++j)
            *(s16x8*)(Btc + ((ad + j * 16) ^ sw)) = rB[j];
    };

    int wm = w >> 2, wn = w & 3;
    int mrow0 = wm * 64;            // wave's 64 rows
    int ncol0 = wn * 128;           // wave's 128 cols
    int lr = lane & 15, lk = (lane >> 4) * 8;

    unsigned aAddr[4], bAddr[8];
#pragma unroll
    for (int m = 0; m < 4; ++m) {
        int r = mrow0 + m * 16 + lr;
        aAddr[m] = (unsigned)(r * 64 + lk * 2) ^ ((unsigned)(r & 7) << 4);
    }
#pragma unroll
    for (int n = 0; n < 8; ++n) {
        int c = ncol0 + n * 16 + lr;
        bAddr[n] = (unsigned)(c * 64 + lk * 2) ^ ((unsigned)(c & 7) << 4);
    }

    f32x4 acc[4][8] = {};

    loadA(0); loadB(0);
    for (int ks = 0; ks < 64; ++ks) {
        __syncthreads();              // previous tile's MFMA reads done
        writeA(); writeB();
        __syncthreads();              // tile visible
        if (ks < 63) { loadA((ks + 1) * 32); loadB((ks + 1) * 32); }  // prefetch under MFMA

        s16x8 af[4], bfr[8];
#pragma unroll
        for (int m = 0; m < 4; ++m) af[m] = *(const s16x8*)(Atc + aAddr[m]);
#pragma unroll
        for (int n = 0; n < 8; ++n) bfr[n] = *(const s16x8*)(Btc + bAddr[n]);
#pragma unroll
        for (int m = 0; m < 4; ++m)
#pragma unroll
            for (int n = 0; n < 8; ++n)
                acc[m][n] = __builtin_amdgcn_mfma_f32_16x16x32_bf16(af[m], bfr[n], acc[m][n], 0, 0, 0);
    }

    // ---- epilogue: att[row] = sum_h relu(p + base[h]) * W_f[h] ----
#pragma unroll
    for (int m = 0; m < 4; ++m) {
        float p0 = 0, p1 = 0, p2 = 0, p3 = 0;
#pragma unroll
        for (int n = 0; n < 8; ++n) {
            int col = ncol0 + n * 16 + lr;
            float bs = bases[col], wfv = wfs[col];
            f32x4 a4 = acc[m][n];
            p0 += fmaxf(a4[0] + bs, 0.f) * wfv;
            p1 += fmaxf(a4[1] + bs, 0.f) * wfv;
            p2 += fmaxf(a4[2] + bs, 0.f) * wfv;
            p3 += fmaxf(a4[3] + bs, 0.f) * wfv;
        }
        float pj[4] = {p0, p1, p2, p3};
#pragma unroll
        for (int j = 0; j < 4; ++j) {
            float s = pj[j];
            s += __shfl_xor(s, 1);
            s += __shfl_xor(s, 2);
            s += __shfl_xor(s, 4);
            s += __shfl_xor(s, 8);   // sum over 16 lanes sharing this row
            if ((lane & 15) == 0) {
                int row = mrow0 + m * 16 + (lane >> 4) * 4 + j;
                att_part[wn][row] = s;   // unique writer per (wn,row)
            }
        }
    }
    __syncthreads();

    if (t < 128) {
        int gr = row0 + t;
        if (gr < A_RG) {
            float s = att_part[0][t] + att_part[1][t] + att_part[2][t] + att_part[3][t];
            att_g[(size_t)b * 256 + gr] = s;
        }
    }
}

// ---------------------------------------------------------------------------
// Kernel 4: softmax over A=196 (wave 0) + weighted sum over regions.
// grid (2 d-chunks, 256 b), block 256; each thread one float4 column group.
// ---------------------------------------------------------------------------
__global__ __launch_bounds__(256) void k_ws(const float* __restrict__ imgs,
                                            const float* __restrict__ att_g,
                                            float* __restrict__ out) {
    __shared__ float alpha_s[256];
    int b = blockIdx.y, dc = blockIdx.x;
    int t = threadIdx.x;

    if (t < 64) {
        float v[4], e[4];
        float mx = -1e30f;
#pragma unroll
        for (int i = 0; i < 4; ++i) {
            int r = i * 64 + t;
            v[i] = (r < A_RG) ? att_g[(size_t)b * 256 + r] : -1e30f;
            mx = fmaxf(mx, v[i]);
        }
        for (int d = 1; d < 64; d <<= 1) mx = fmaxf(mx, __shfl_xor(mx, d));
        float sum = 0.f;
#pragma unroll
        for (int i = 0; i < 4; ++i) {
            int r = i * 64 + t;
            e[i] = (r < A_RG) ? __expf(v[i] - mx) : 0.f;
            sum += e[i];
        }
        for (int d = 1; d < 64; d <<= 1) sum += __shfl_xor(sum, d);
        float inv = 1.0f / sum;
#pragma unroll
        for (int i = 0; i < 4; ++i) alpha_s[i * 64 + t] = e[i] * inv;
    }
    __syncthreads();

    const float* imgb = imgs + (size_t)b * A_RG * DVD;
    int col = dc * 1024 + t * 4;
    f32x4 o = {};
#pragma unroll 4
    for (int a = 0; a < A_RG; ++a) {
        float al = alpha_s[a];
        f32x4 v = *(const f32x4*)(imgb + (size_t)a * DVD + col);
        o[0] = fmaf(al, v[0], o[0]);
        o[1] = fmaf(al, v[1], o[1]);
        o[2] = fmaf(al, v[2], o[2]);
        o[3] = fmaf(al, v[3], o[3]);
    }
    *(f32x4*)(out + (size_t)b * DVD + col) = o;
}

// ---------------------------------------------------------------------------
extern "C" void kernel_launch(void* const* d_in, const int* in_sizes, int n_in,
                              void* d_out, int out_size, void* d_ws, size_t ws_size,
                              hipStream_t stream) {
    const float* h_att   = (const float*)d_in[0];
    const float* prev_h2 = (const float*)d_in[1];
    const float* imgs    = (const float*)d_in[2];
    const float* W_v     = (const float*)d_in[3];
    const float* b_v     = (const float*)d_in[4];
    const float* W_ha    = (const float*)d_in[5];
    const float* b_ha    = (const float*)d_in[6];
    const float* W_hv    = (const float*)d_in[7];
    const float* b_hv    = (const float*)d_in[8];
    const float* W_f     = (const float*)d_in[9];
    // d_in[10] = b_f: softmax-invariant additive constant -> unused

    // ws layout: [0,2MB) Wt bf16 [512][2048]; [2MB,2.5MB) base fp32 [256][512];
    //            [2.5MB,2.75MB) att fp32 [256][256]
    unsigned short* Wt = (unsigned short*)d_ws;
    float* base_g = (float*)((char*)d_ws + (size_t)DVD * H_SZ * 2);
    float* att_g  = (float*)((char*)d_ws + (size_t)DVD * H_SZ * 2 + (size_t)B_SZ * H_SZ * 4);
    float* out = (float*)d_out;

    hipLaunchKernelGGL(k_prepW, dim3(256), dim3(256), 0, stream, W_v, Wt);
    hipLaunchKernelGGL(k_base, dim3(256), dim3(256), 0, stream,
                       h_att, prev_h2, W_ha, b_ha, W_hv, b_hv, b_v, base_g);
    hipLaunchKernelGGL(k_gemm, dim3(512), dim3(512), 0, stream,
                       imgs, Wt, base_g, W_f, att_g);
    hipLaunchKernelGGL(k_ws, dim3(2, 256), dim3(256), 0, stream,
                       imgs, att_g, out);
}

// Round 3
// 386.234 us; speedup vs baseline: 4.2715x; 1.1013x over previous
//
#include <hip/hip_runtime.h>
#include <stdint.h>

typedef float f32x4 __attribute__((ext_vector_type(4)));
typedef short s16x8 __attribute__((ext_vector_type(8)));

#define B_SZ 256
#define A_RG 196
#define DVD  2048
#define RNN  1024
#define H_SZ 512
#define M_TOT (B_SZ * A_RG)   // 50176 flat rows
#define BM 128
#define BK 32

__device__ __forceinline__ unsigned short f2bf(float f) {
    unsigned u = __builtin_bit_cast(unsigned, f);
    u = u + 0x7FFFu + ((u >> 16) & 1u);   // RNE
    return (unsigned short)(u >> 16);
}

// ---------------------------------------------------------------------------
// Kernel 1: W_v [2048,512] fp32 -> Wt [512,2048] bf16 (transposed, k-contig)
// ---------------------------------------------------------------------------
__global__ __launch_bounds__(256) void k_prepW(const float* __restrict__ Wv,
                                               unsigned short* __restrict__ Wt) {
    __shared__ float tile[64][65];
    int kt = blockIdx.x >> 3, ct = blockIdx.x & 7;
    int k0 = kt * 64, c0 = ct * 64;
    int t = threadIdx.x;
    int cl = t & 63, rq = t >> 6;
#pragma unroll
    for (int i = 0; i < 16; ++i) {
        int r = rq * 16 + i;
        tile[r][cl] = Wv[(size_t)(k0 + r) * H_SZ + c0 + cl];
    }
    __syncthreads();
    int kl = t & 63;
#pragma unroll
    for (int i = 0; i < 16; ++i) {
        int cr = rq * 16 + i;
        Wt[(size_t)(c0 + cr) * DVD + k0 + kl] = f2bf(tile[kl][cr]);
    }
}

// ---------------------------------------------------------------------------
// Kernel 2: base[b,h] = h_att[b]@W_ha + prev_h2[b]@W_hv + b_ha + b_hv + b_v
// ---------------------------------------------------------------------------
__global__ __launch_bounds__(256) void k_base(const float* __restrict__ h_att,
                                              const float* __restrict__ prev_h2,
                                              const float* __restrict__ W_ha,
                                              const float* __restrict__ b_ha,
                                              const float* __restrict__ W_hv,
                                              const float* __restrict__ b_hv,
                                              const float* __restrict__ b_v,
                                              float* __restrict__ base_g) {
    __shared__ float ha_s[4][RNN];
    __shared__ float pv_s[4][RNN];
    int bg = blockIdx.x >> 2, hg = blockIdx.x & 3;
    int t = threadIdx.x;
#pragma unroll
    for (int i = 0; i < 16; ++i) {
        int idx = i * 256 + t;
        int bl = idx >> 10, k = idx & 1023;
        ha_s[bl][k] = h_att[(size_t)(bg * 4 + bl) * RNN + k];
        pv_s[bl][k] = prev_h2[(size_t)(bg * 4 + bl) * RNN + k];
    }
    __syncthreads();
    int h = hg * 128 + (t & 127);
    int br = t >> 7;
    float aA0 = 0, aA1 = 0, aV0 = 0, aV1 = 0;
#pragma unroll 4
    for (int k = 0; k < RNN; ++k) {
        float w1 = W_ha[(size_t)k * H_SZ + h];
        float w2 = W_hv[(size_t)k * H_SZ + h];
        aA0 = fmaf(ha_s[br * 2][k],     w1, aA0);
        aA1 = fmaf(ha_s[br * 2 + 1][k], w1, aA1);
        aV0 = fmaf(pv_s[br * 2][k],     w2, aV0);
        aV1 = fmaf(pv_s[br * 2 + 1][k], w2, aV1);
    }
    float bias = b_ha[h] + b_hv[h] + b_v[h];
    base_g[(size_t)(bg * 4 + br * 2) * H_SZ + h]     = aA0 + aV0 + bias;
    base_g[(size_t)(bg * 4 + br * 2 + 1) * H_SZ + h] = aA1 + aV1 + bias;
}

// ---------------------------------------------------------------------------
// Kernel 3: flat-M GEMM [50176,2048]x[2048,512] bf16 MFMA, fused score.
// grid 392 (one per 128-row tile), block 512 = 8 waves (2M x 4N, wave 64x128).
// Double-buffered LDS, 1 barrier per K-tile, prefetch-issue-early (T14/T3),
// swizzle ^(((row>>1)&3)<<4) on 64B-stride tiles, setprio on MFMA cluster.
// ---------------------------------------------------------------------------
__global__ __launch_bounds__(512, 2) void k_gemm(const float* __restrict__ imgs,
                                                 const unsigned short* __restrict__ Wt,
                                                 const float* __restrict__ base_g,
                                                 const float* __restrict__ W_f,
                                                 float* __restrict__ att_g) {
    __shared__ short A_s[2][BM * BK];      // 2 x 8 KB
    __shared__ short B_s[2][H_SZ * BK];    // 2 x 32 KB
    __shared__ float wf_s[H_SZ];
    __shared__ float base_s[2][H_SZ];
    __shared__ float att_part[4][BM];

    int mtile = blockIdx.x;
    int m0 = mtile * BM;
    int t = threadIdx.x;
    int lane = t & 63, w = t >> 6;
    int b0 = m0 / A_RG;

    wf_s[t < H_SZ ? t : 0] = W_f[t < H_SZ ? t : 0];   // t always < 512 == H_SZ
    base_s[0][t] = base_g[(size_t)b0 * H_SZ + t];
    int b1 = min(b0 + 1, B_SZ - 1);
    base_s[1][t] = base_g[(size_t)b1 * H_SZ + t];

    // ---- staging maps ----
    // A: thread -> row = t>>2 (128 rows), k floats (t&3)*8 .. +7  (2 float4)
    int arow = t >> 2;
    int akb  = (t & 3) * 16;                 // byte offset within 64B LDS row
    const float* Ag = imgs + (size_t)(m0 + arow) * DVD + (t & 3) * 8;
    unsigned aw = (unsigned)((arow * 64 + akb) ^ (((arow >> 1) & 3) << 4));
    // B: 4 rounds j, col = 128j + (t>>2), k bf16 (t&3)*8 .. +7 (1 s16x8 each)
    int bcol = t >> 2;
    const unsigned short* Bg = Wt + (size_t)bcol * DVD + (t & 3) * 8;
    unsigned bw = (unsigned)((bcol * 64 + akb) ^ (((bcol >> 1) & 3) << 4));

    float4 sA0, sA1;
    s16x8 sB[4];

    auto loadT = [&](int k0) {
        const float4* ap = (const float4*)(Ag + k0);
        sA0 = ap[0]; sA1 = ap[1];
#pragma unroll
        for (int j = 0; j < 4; ++j)
            sB[j] = *(const s16x8*)(Bg + (size_t)j * 128 * DVD + k0);
    };
    auto storeT = [&](int buf) {
        char* Ac = (char*)A_s[buf];
        char* Bc = (char*)B_s[buf];
        s16x8 v;
        v[0] = (short)f2bf(sA0.x); v[1] = (short)f2bf(sA0.y);
        v[2] = (short)f2bf(sA0.z); v[3] = (short)f2bf(sA0.w);
        v[4] = (short)f2bf(sA1.x); v[5] = (short)f2bf(sA1.y);
        v[6] = (short)f2bf(sA1.z); v[7] = (short)f2bf(sA1.w);
        *(s16x8*)(Ac + aw) = v;
#pragma unroll
        for (int j = 0; j < 4; ++j)
            *(s16x8*)(Bc + bw + j * 8192) = sB[j];
    };

    // ---- fragment read addresses (swizzled, 64B-stride rows) ----
    int wm = w >> 2, wn = w & 3;          // 2M x 4N wave grid
    int lr = lane & 15, lk2 = (lane >> 4) * 16;   // byte k-offset
    unsigned aAddr[4], bAddr[8];
#pragma unroll
    for (int m = 0; m < 4; ++m) {
        int r = wm * 64 + m * 16 + lr;
        aAddr[m] = (unsigned)((r * 64 + lk2) ^ (((r >> 1) & 3) << 4));
    }
#pragma unroll
    for (int n = 0; n < 8; ++n) {
        int c = wn * 128 + n * 16 + lr;
        bAddr[n] = (unsigned)((c * 64 + lk2) ^ (((c >> 1) & 3) << 4));
    }

    f32x4 acc[4][8] = {};

    // prologue
    loadT(0);
    storeT(0);
    __syncthreads();

    for (int kt = 0; kt < DVD / BK; ++kt) {          // 64 K-tiles
        int cur = kt & 1;
        if (kt < DVD / BK - 1) loadT((kt + 1) * BK); // issue prefetch EARLY
        __builtin_amdgcn_sched_barrier(0);           // keep loads above compute
        const char* Ac = (const char*)A_s[cur];
        const char* Bc = (const char*)B_s[cur];
        __builtin_amdgcn_s_setprio(1);
        s16x8 bfr[8];
#pragma unroll
        for (int n = 0; n < 8; ++n) bfr[n] = *(const s16x8*)(Bc + bAddr[n]);
#pragma unroll
        for (int m = 0; m < 4; ++m) {
            s16x8 af = *(const s16x8*)(Ac + aAddr[m]);
#pragma unroll
            for (int n = 0; n < 8; ++n)
                acc[m][n] = __builtin_amdgcn_mfma_f32_16x16x32_bf16(af, bfr[n], acc[m][n], 0, 0, 0);
        }
        __builtin_amdgcn_s_setprio(0);
        if (kt < DVD / BK - 1) storeT(cur ^ 1);      // write-late into other buffer
        __syncthreads();
    }

    // ---- epilogue: att[row] = sum_h relu(p + base[b(row),h]) * W_f[h] ----
#pragma unroll
    for (int m = 0; m < 4; ++m) {
        float pj[4] = {0.f, 0.f, 0.f, 0.f};
#pragma unroll
        for (int n = 0; n < 8; ++n) {
            int col = wn * 128 + n * 16 + lr;
            float wfv = wf_s[col];
            f32x4 a4 = acc[m][n];
#pragma unroll
            for (int j = 0; j < 4; ++j) {
                int row = wm * 64 + m * 16 + (lane >> 4) * 4 + j;
                int bi = (m0 + row) / A_RG - b0;     // 0 or 1
                pj[j] += fmaxf(a4[j] + base_s[bi][col], 0.f) * wfv;
            }
        }
#pragma unroll
        for (int j = 0; j < 4; ++j) {
            float s = pj[j];
            s += __shfl_xor(s, 1);
            s += __shfl_xor(s, 2);
            s += __shfl_xor(s, 4);
            s += __shfl_xor(s, 8);    // sum over 16 lanes sharing this row
            if (lr == 0) {
                int row = wm * 64 + m * 16 + (lane >> 4) * 4 + j;
                att_part[wn][row] = s;    // unique writer per (wn,row)
            }
        }
    }
    __syncthreads();

    if (t < BM) {
        att_g[m0 + t] = att_part[0][t] + att_part[1][t] + att_part[2][t] + att_part[3][t];
    }
}

// ---------------------------------------------------------------------------
// Kernel 4: softmax over A=196 + weighted sum over regions.
// grid (2 d-chunks, 256 b), block 256; each thread one float4 column group.
// ---------------------------------------------------------------------------
__global__ __launch_bounds__(256) void k_ws(const float* __restrict__ imgs,
                                            const float* __restrict__ att_g,
                                            float* __restrict__ out) {
    __shared__ float alpha_s[256];
    int b = blockIdx.y, dc = blockIdx.x;
    int t = threadIdx.x;

    if (t < 64) {
        float v[4], e[4];
        float mx = -1e30f;
#pragma unroll
        for (int i = 0; i < 4; ++i) {
            int r = i * 64 + t;
            v[i] = (r < A_RG) ? att_g[(size_t)b * A_RG + r] : -1e30f;
            mx = fmaxf(mx, v[i]);
        }
        for (int d = 1; d < 64; d <<= 1) mx = fmaxf(mx, __shfl_xor(mx, d));
        float sum = 0.f;
#pragma unroll
        for (int i = 0; i < 4; ++i) {
            int r = i * 64 + t;
            e[i] = (r < A_RG) ? __expf(v[i] - mx) : 0.f;
            sum += e[i];
        }
        for (int d = 1; d < 64; d <<= 1) sum += __shfl_xor(sum, d);
        float inv = 1.0f / sum;
#pragma unroll
        for (int i = 0; i < 4; ++i) alpha_s[i * 64 + t] = e[i] * inv;
    }
    __syncthreads();

    const float* imgb = imgs + (size_t)b * A_RG * DVD;
    int col = dc * 1024 + t * 4;
    f32x4 o = {};
#pragma unroll 4
    for (int a = 0; a < A_RG; ++a) {
        float al = alpha_s[a];
        f32x4 v = *(const f32x4*)(imgb + (size_t)a * DVD + col);
        o[0] = fmaf(al, v[0], o[0]);
        o[1] = fmaf(al, v[1], o[1]);
        o[2] = fmaf(al, v[2], o[2]);
        o[3] = fmaf(al, v[3], o[3]);
    }
    *(f32x4*)(out + (size_t)b * DVD + col) = o;
}

// ---------------------------------------------------------------------------
extern "C" void kernel_launch(void* const* d_in, const int* in_sizes, int n_in,
                              void* d_out, int out_size, void* d_ws, size_t ws_size,
                              hipStream_t stream) {
    const float* h_att   = (const float*)d_in[0];
    const float* prev_h2 = (const float*)d_in[1];
    const float* imgs    = (const float*)d_in[2];
    const float* W_v     = (const float*)d_in[3];
    const float* b_v     = (const float*)d_in[4];
    const float* W_ha    = (const float*)d_in[5];
    const float* b_ha    = (const float*)d_in[6];
    const float* W_hv    = (const float*)d_in[7];
    const float* b_hv    = (const float*)d_in[8];
    const float* W_f     = (const float*)d_in[9];
    // d_in[10] = b_f: softmax-invariant additive constant -> unused

    // ws layout: [0,2MB) Wt bf16 [512][2048]; [2MB,+512KB) base fp32 [256][512];
    //            [+512KB,+200KB) att fp32 [50176]
    unsigned short* Wt = (unsigned short*)d_ws;
    float* base_g = (float*)((char*)d_ws + (size_t)DVD * H_SZ * 2);
    float* att_g  = (float*)((char*)d_ws + (size_t)DVD * H_SZ * 2 + (size_t)B_SZ * H_SZ * 4);
    float* out = (float*)d_out;

    hipLaunchKernelGGL(k_prepW, dim3(256), dim3(256), 0, stream, W_v, Wt);
    hipLaunchKernelGGL(k_base, dim3(256), dim3(256), 0, stream,
                       h_att, prev_h2, W_ha, b_ha, W_hv, b_hv, b_v, base_g);
    hipLaunchKernelGGL(k_gemm, dim3(M_TOT / BM), dim3(512), 0, stream,
                       imgs, Wt, base_g, W_f, att_g);
    hipLaunchKernelGGL(k_ws, dim3(2, B_SZ), dim3(256), 0, stream,
                       imgs, att_g, out);
}